// Round 6
// baseline (218.317 us; speedup 1.0000x reference)
//
#include <hip/hip_runtime.h>

// Problem constants (from reference setup_inputs)
#define B_ 2
#define D_ 160
#define H_ 192
#define W_ 160

constexpr int HW_  = H_ * W_;          // 30720
constexpr int DHW_ = D_ * HW_;         // 4915200

// Output tile per block (256 threads, 8 voxels/thread along z)
#define TX 32
#define TY 8
#define TZ 8
// Asymmetric halos: x [-4,+3] (keeps 16B-aligned DMA source), y [-3,+4], z [-3,+3]
#define HX 4
#define HY 3
#define HZ 3
#define SXT 40                         // 32+4+3=39 -> pad 40 (10 float4 slots)
#define SYT 16                         // 8+3+4
#define SZT 15                         // 8+3+3
#define NSLOT (SZT * SYT * 10)         // 2400 float4 slots
#define NITER 10
#define TAILN (NSLOT - 256 * (NITER - 1))   // 96

__device__ __forceinline__ void gload_lds16(const float* g, float* l) {
    __builtin_amdgcn_global_load_lds(
        (const __attribute__((address_space(1))) unsigned int*)g,
        (__attribute__((address_space(3))) unsigned int*)l,
        16, 0, 0);
}

// Exact fallback for far-flow voxels: clamped global gather + zero-pad weights.
__device__ __forceinline__ float sample_global(const float* __restrict__ sp,
                                               float z, float y, float x) {
    const float zf = floorf(z), yf = floorf(y), xf = floorf(x);
    const int z0 = (int)zf, y0 = (int)yf, x0 = (int)xf;
    const int z1 = z0 + 1, y1 = y0 + 1, x1 = x0 + 1;
    float wz1 = z - zf, wy1 = y - yf, wx1 = x - xf;
    float wz0 = 1.f - wz1, wy0 = 1.f - wy1, wx0 = 1.f - wx1;
    wz0 = ((unsigned)z0 < (unsigned)D_) ? wz0 : 0.f;
    wz1 = ((unsigned)z1 < (unsigned)D_) ? wz1 : 0.f;
    wy0 = ((unsigned)y0 < (unsigned)H_) ? wy0 : 0.f;
    wy1 = ((unsigned)y1 < (unsigned)H_) ? wy1 : 0.f;
    wx0 = ((unsigned)x0 < (unsigned)W_) ? wx0 : 0.f;
    wx1 = ((unsigned)x1 < (unsigned)W_) ? wx1 : 0.f;
    const int z0c = min(max(z0, 0), D_ - 1), z1c = min(max(z1, 0), D_ - 1);
    const int y0c = min(max(y0, 0), H_ - 1), y1c = min(max(y1, 0), H_ - 1);
    const int x0c = min(max(x0, 0), W_ - 1), x1c = min(max(x1, 0), W_ - 1);
    const float* p00 = sp + (size_t)z0c * HW_ + (size_t)y0c * W_;
    const float* p01 = sp + (size_t)z0c * HW_ + (size_t)y1c * W_;
    const float* p10 = sp + (size_t)z1c * HW_ + (size_t)y0c * W_;
    const float* p11 = sp + (size_t)z1c * HW_ + (size_t)y1c * W_;
    const float v000 = p00[x0c], v001 = p00[x1c];
    const float v010 = p01[x0c], v011 = p01[x1c];
    const float v100 = p10[x0c], v101 = p10[x1c];
    const float v110 = p11[x0c], v111 = p11[x1c];
    return ((v000 * wx0 + v001 * wx1) * wy0 + (v010 * wx0 + v011 * wx1) * wy1) * wz0
         + ((v100 * wx0 + v101 * wx1) * wy0 + (v110 * wx0 + v111 * wx1) * wy1) * wz1;
}

// 4 waves/EU: matches the LDS-limited 4 blocks/CU and unlocks 128 VGPRs for ILP.
__global__ __launch_bounds__(256, 4) void st3d_kernel(const float* __restrict__ src,
                                                      const float* __restrict__ flow,
                                                      float* __restrict__ out) {
    __shared__ float tile[SZT * SYT * SXT];   // 38,400 B -> 4 blocks/CU

    const float SZf = (float)D_ / (float)(D_ - 1);
    const float SYf = (float)H_ / (float)(H_ - 1);
    const float SXf = (float)W_ / (float)(W_ - 1);

    const int tid = threadIdx.x;
    const int bx = blockIdx.x, by = blockIdx.y, bzb = blockIdx.z;
    const int b  = bzb / (D_ / TZ);
    const int bz = bzb % (D_ / TZ);

    const int oxi = bx * TX - HX;
    const int oyi = by * TY - HY;
    const int ozi = bz * TZ - HZ;

    const float* __restrict__ sp = src + (size_t)b * DHW_;   // C == 1
    const bool interior = (bx >= 1) & (bx <= 3) & (by >= 1) & (by <= 22) & (bz >= 1) & (bz <= 18);

    // ---- flow prefetch FIRST (their results become usable at vmcnt(10),
    //      i.e. while the staging DMAs are still in flight) ----
    const int lxl = tid & (TX - 1);
    const int lyl = tid >> 5;
    const int w = bx * TX + lxl;
    const int h = by * TY + lyl;
    const float* __restrict__ fb = flow + (size_t)b * 3 * DHW_;
    const int s0 = (bz * TZ) * HW_ + h * W_ + w;
    float fza[TZ], fya[TZ], fxa[TZ];
    #pragma unroll
    for (int k = 0; k < TZ; ++k) {
        fza[k] = fb[s0 + k * HW_];
        fya[k] = fb[DHW_ + s0 + k * HW_];
        fxa[k] = fb[2 * DHW_ + s0 + k * HW_];
    }

    // slot l = x4 + 10*yy + 160*zz ; thread handles l = tid + 256*i
    const int r0 = tid / 10;
    int x4 = tid - r0 * 10;
    int yy = r0 & 15;
    int zz = r0 >> 4;

    if (interior) {
        const float* gbase = sp + (size_t)ozi * HW_ + oyi * W_ + oxi;
        #pragma unroll
        for (int i = 0; i < NITER; ++i) {
            if (i < NITER - 1 || tid < TAILN) {
                gload_lds16(gbase + zz * HW_ + yy * W_ + 4 * x4,
                            &tile[4 * (tid + 256 * i)]);
            }
            x4 += 6; if (x4 >= 10) { x4 -= 10; yy += 1; }
            yy += 9; zz += 1; if (yy >= 16) { yy -= 16; zz += 1; }
        }
    } else {
        float4 v[NITER];
        int x4b = x4, yyb = yy, zzb = zz;
        #pragma unroll
        for (int i = 0; i < NITER; ++i) {
            if (i < NITER - 1 || tid < TAILN) {
                const int gz = min(max(ozi + zzb, 0), D_ - 1);
                const int gy = min(max(oyi + yyb, 0), H_ - 1);
                const int gx0 = oxi + 4 * x4b;
                const float* rowp = sp + (size_t)gz * HW_ + (size_t)gy * W_;
                if (gx0 >= 0 && gx0 <= W_ - 4) {
                    v[i] = *(const float4*)(rowp + gx0);
                } else {
                    v[i].x = rowp[min(max(gx0 + 0, 0), W_ - 1)];
                    v[i].y = rowp[min(max(gx0 + 1, 0), W_ - 1)];
                    v[i].z = rowp[min(max(gx0 + 2, 0), W_ - 1)];
                    v[i].w = rowp[min(max(gx0 + 3, 0), W_ - 1)];
                }
            }
            x4b += 6; if (x4b >= 10) { x4b -= 10; yyb += 1; }
            yyb += 9; zzb += 1; if (yyb >= 16) { yyb -= 16; zzb += 1; }
        }
        #pragma unroll
        for (int i = 0; i < NITER; ++i) {
            if (i < NITER - 1 || tid < TAILN)
                *(float4*)&tile[4 * (tid + 256 * i)] = v[i];
        }
    }

    // ---- PRE-BARRIER precompute: all flow-dependent VALU runs in the DMA
    //      drain shadow (needs only the flow registers). ----
    const float c_y = h * SYf - 0.5f;
    const float c_x = w * SXf - 0.5f;
    const float c_z = (bz * TZ) * SZf - 0.5f;

    float zv[TZ], yv[TZ], xv[TZ];
    #pragma unroll
    for (int k = 0; k < TZ; ++k) {
        zv[k] = fmaf(fza[k], SZf, c_z + k * SZf);
        yv[k] = fmaf(fya[k], SYf, c_y);
        xv[k] = fmaf(fxa[k], SXf, c_x);
    }

    int  idxA[TZ];
    float tzA[TZ], tyA[TZ], txA[TZ];
    bool okA[TZ];
    if (interior) {
        #pragma unroll
        for (int k = 0; k < TZ; ++k) {
            const float zf = floorf(zv[k]), yf = floorf(yv[k]), xf = floorf(xv[k]);
            const int az0 = (int)zf - ozi;
            const int ay0 = (int)yf - oyi;
            const int ax0 = (int)xf - oxi;
            okA[k] = ((unsigned)az0 <= SZT - 2) & ((unsigned)ay0 <= SYT - 2) & ((unsigned)ax0 <= SXT - 2);
            idxA[k] = okA[k] ? ((az0 * SYT + ay0) * SXT + ax0) : 0;
            tzA[k] = zv[k] - zf; tyA[k] = yv[k] - yf; txA[k] = xv[k] - xf;
        }
    }

    __syncthreads();

    const size_t obase = (size_t)b * DHW_ + (size_t)s0;

    if (interior) {
        // Batches of 4 voxels: 32 ds_reads in flight before any lerp consumes.
        #pragma unroll
        for (int kb = 0; kb < TZ; kb += 4) {
            float tv[4][8];
            #pragma unroll
            for (int j = 0; j < 4; ++j) {
                const int id = idxA[kb + j];
                tv[j][0] = tile[id];                       tv[j][1] = tile[id + 1];
                tv[j][2] = tile[id + SXT];                 tv[j][3] = tile[id + SXT + 1];
                tv[j][4] = tile[id + SYT * SXT];           tv[j][5] = tile[id + SYT * SXT + 1];
                tv[j][6] = tile[id + SYT * SXT + SXT];     tv[j][7] = tile[id + SYT * SXT + SXT + 1];
            }
            #pragma unroll
            for (int j = 0; j < 4; ++j) {
                const int k = kb + j;
                const float tx = txA[k], ty = tyA[k], tz = tzA[k];
                const float a0 = tv[j][0] + tx * (tv[j][1] - tv[j][0]);
                const float a1 = tv[j][2] + tx * (tv[j][3] - tv[j][2]);
                const float a2 = tv[j][4] + tx * (tv[j][5] - tv[j][4]);
                const float a3 = tv[j][6] + tx * (tv[j][7] - tv[j][6]);
                const float b0 = a0 + ty * (a1 - a0);
                const float b1 = a2 + ty * (a3 - a2);
                float r = b0 + tz * (b1 - b0);
                if (!okA[k]) r = sample_global(sp, zv[k], yv[k], xv[k]);  // rare
                out[obase + (size_t)k * HW_] = r;
            }
        }
    } else {
        #pragma unroll
        for (int k = 0; k < TZ; ++k) {
            const float z = zv[k], y = yv[k], x = xv[k];
            const float zf = floorf(z), yf = floorf(y), xf = floorf(x);
            const int z0 = (int)zf, y0 = (int)yf, x0 = (int)xf;
            const int z1 = z0 + 1, y1 = y0 + 1, x1 = x0 + 1;
            float wz1 = z - zf, wy1 = y - yf, wx1 = x - xf;
            float wz0 = 1.f - wz1, wy0 = 1.f - wy1, wx0 = 1.f - wx1;
            wz0 = ((unsigned)z0 < (unsigned)D_) ? wz0 : 0.f;
            wz1 = ((unsigned)z1 < (unsigned)D_) ? wz1 : 0.f;
            wy0 = ((unsigned)y0 < (unsigned)H_) ? wy0 : 0.f;
            wy1 = ((unsigned)y1 < (unsigned)H_) ? wy1 : 0.f;
            wx0 = ((unsigned)x0 < (unsigned)W_) ? wx0 : 0.f;
            wx1 = ((unsigned)x1 < (unsigned)W_) ? wx1 : 0.f;
            const int z0c = min(max(z0, 0), D_ - 1), z1c = min(max(z1, 0), D_ - 1);
            const int y0c = min(max(y0, 0), H_ - 1), y1c = min(max(y1, 0), H_ - 1);
            const int x0c = min(max(x0, 0), W_ - 1), x1c = min(max(x1, 0), W_ - 1);
            float r;
            const bool inTile = ((unsigned)(z0c - ozi) <= SZT - 2) &&
                                ((unsigned)(y0c - oyi) <= SYT - 2) &&
                                ((unsigned)(x0c - oxi) <= SXT - 2);
            if (inTile) {
                const int az0 = z0c - ozi, az1 = z1c - ozi;
                const int ay0 = y0c - oyi, ay1 = y1c - oyi;
                const int ax0 = x0c - oxi, ax1 = x1c - oxi;
                const int q00 = (az0 * SYT + ay0) * SXT;
                const int q01 = (az0 * SYT + ay1) * SXT;
                const int q10 = (az1 * SYT + ay0) * SXT;
                const int q11 = (az1 * SYT + ay1) * SXT;
                const float v000 = tile[q00 + ax0], v001 = tile[q00 + ax1];
                const float v010 = tile[q01 + ax0], v011 = tile[q01 + ax1];
                const float v100 = tile[q10 + ax0], v101 = tile[q10 + ax1];
                const float v110 = tile[q11 + ax0], v111 = tile[q11 + ax1];
                r = ((v000 * wx0 + v001 * wx1) * wy0 + (v010 * wx0 + v011 * wx1) * wy1) * wz0
                  + ((v100 * wx0 + v101 * wx1) * wy0 + (v110 * wx0 + v111 * wx1) * wy1) * wz1;
            } else {
                const float* p00 = sp + (size_t)z0c * HW_ + (size_t)y0c * W_;
                const float* p01 = sp + (size_t)z0c * HW_ + (size_t)y1c * W_;
                const float* p10 = sp + (size_t)z1c * HW_ + (size_t)y0c * W_;
                const float* p11 = sp + (size_t)z1c * HW_ + (size_t)y1c * W_;
                const float v000 = p00[x0c], v001 = p00[x1c];
                const float v010 = p01[x0c], v011 = p01[x1c];
                const float v100 = p10[x0c], v101 = p10[x1c];
                const float v110 = p11[x0c], v111 = p11[x1c];
                r = ((v000 * wx0 + v001 * wx1) * wy0 + (v010 * wx0 + v011 * wx1) * wy1) * wz0
                  + ((v100 * wx0 + v101 * wx1) * wy0 + (v110 * wx0 + v111 * wx1) * wy1) * wz1;
            }
            out[obase + (size_t)k * HW_] = r;
        }
    }
}

extern "C" void kernel_launch(void* const* d_in, const int* in_sizes, int n_in,
                              void* d_out, int out_size, void* d_ws, size_t ws_size,
                              hipStream_t stream) {
    const float* src  = (const float*)d_in[0];
    const float* flow = (const float*)d_in[1];
    float* out = (float*)d_out;

    dim3 grid(W_ / TX, H_ / TY, (D_ / TZ) * B_);   // 5 x 24 x 40 = 4800 blocks
    st3d_kernel<<<grid, dim3(256), 0, stream>>>(src, flow, out);
}